// Round 3
// baseline (536.224 us; speedup 1.0000x reference)
//
#include <hip/hip_runtime.h>

// Problem constants: B=4, C=16, H=W=1024, labels 0..512.
#define B_IMG 4
#define CCH 16
#define HALF_C 8         // channels per block (channel-split for occupancy)
#define HW (1024 * 1024)
#define SEG 513          // slot 0 = background
#define PADU 9           // u64 stride per label: odd => labels scatter over all 16 bank-pairs
#define THREADS 512
#define BLOCKS_PER_IMG 128
#define GRID (B_IMG * BLOCKS_PER_IMG * 2)        // 1024 blocks (x2 channel halves)
#define PIX_PER_BLOCK (HW / BLOCKS_PER_IMG)      // 8192
#define QUADS (PIX_PER_BLOCK / (THREADS * 4))    // 4 float4-quads per thread

// Fixed-point: each add contributes round(v*2^13) + 2^17 (bias keeps both u32 halves
// positive; bias is removed at finalize using the exact global count).
#define FXSCALE 8192.0f
#define FXINV   (1.0f / 8192.0f)
#define FXBIAS  131072.0f        // 1<<17

// Workspace (floats): ws_pred[B][SEG][C] (biased fixed sums), ws_tgt same, ws_cnt[B][SEG]
#define WS_PRED 0
#define WS_TGT  (B_IMG * SEG * CCH)              // 32832
#define WS_CNT  (2 * B_IMG * SEG * CCH)          // 65664
#define WS_FLOATS (WS_CNT + B_IMG * SEG)         // 67716

// Output (floats): pred_means[2048*16], target_means[2048*16], cell_ids[2048]
#define OUT_TGT  (B_IMG * 512 * CCH)             // 32768
#define OUT_CELL (2 * B_IMG * 512 * CCH)         // 65536

typedef float v4f __attribute__((ext_vector_type(4)));

__device__ __forceinline__ unsigned long long pack2(float p, float t) {
    unsigned int ip = (unsigned int)(__float2int_rn(p * FXSCALE) + 131072);
    unsigned int it = (unsigned int)(__float2int_rn(t * FXSCALE) + 131072);
    return (unsigned long long)ip | ((unsigned long long)it << 32);
}

__global__ __launch_bounds__(THREADS, 8)
void accum_kernel(const float* __restrict__ pred,
                  const float* __restrict__ target,
                  const int* __restrict__ nuclei,
                  float* __restrict__ ws) {
    // s_acc[label][cc]: lo 32b = pred biased fixed-sum, hi 32b = target biased fixed-sum
    __shared__ unsigned long long s_acc[SEG * PADU];   // 36.9 KB -> 4 blocks/CU
    __shared__ unsigned int s_cnt[SEG];                // used by h==0 blocks only

    const int tid = threadIdx.x;
    for (int i = tid; i < SEG * PADU; i += THREADS) s_acc[i] = 0ull;
    for (int i = tid; i < SEG; i += THREADS) s_cnt[i] = 0u;
    __syncthreads();

    const int gb  = blockIdx.x;
    const int h   = gb & 1;                  // channel half: 0 -> c 0..7 (+counts), 1 -> c 8..15
    const int rb  = gb >> 1;
    const int b   = rb / BLOCKS_PER_IMG;
    const int blk = rb % BLOCKS_PER_IMG;
    const int c0  = h * HALF_C;

    const int*   nuc = nuclei + b * HW + blk * PIX_PER_BLOCK;
    const float* pr  = pred   + (size_t)(b * CCH + c0) * HW + blk * PIX_PER_BLOCK;
    const float* tg  = target + (size_t)(b * CCH + c0) * HW + blk * PIX_PER_BLOCK;

    for (int q = 0; q < QUADS; ++q) {
        const int p = (q * THREADS + tid) * 4;          // coalesced 16B/lane
        const int4 lab = *(const int4*)(nuc + p);

        unsigned long long* a0 = &s_acc[lab.x * PADU];
        unsigned long long* a1 = &s_acc[lab.y * PADU];
        unsigned long long* a2 = &s_acc[lab.z * PADU];
        unsigned long long* a3 = &s_acc[lab.w * PADU];

        if (h == 0) {   // wave-uniform branch; counts accumulated once total
            atomicAdd(&s_cnt[lab.x], 1u);
            atomicAdd(&s_cnt[lab.y], 1u);
            atomicAdd(&s_cnt[lab.z], 1u);
            atomicAdd(&s_cnt[lab.w], 1u);
        }

#pragma unroll
        for (int c = 0; c < HALF_C; ++c) {
            const v4f pv = __builtin_nontemporal_load((const v4f*)(pr + c * HW + p));
            const v4f tv = __builtin_nontemporal_load((const v4f*)(tg + c * HW + p));
            atomicAdd(a0 + c, pack2(pv.x, tv.x));
            atomicAdd(a1 + c, pack2(pv.y, tv.y));
            atomicAdd(a2 + c, pack2(pv.z, tv.z));
            atomicAdd(a3 + c, pack2(pv.w, tv.w));
        }
    }
    __syncthreads();

    // Flush biased fixed sums (exact ints < 2^24 per block) into global f32 accumulators.
    float* ws_pred = ws + WS_PRED + b * SEG * CCH;
    float* ws_tgt  = ws + WS_TGT  + b * SEG * CCH;
    float* ws_cnt  = ws + WS_CNT  + b * SEG;
    for (int i = tid; i < SEG * HALF_C; i += THREADS) {
        const int sg = i >> 3, cc = i & 7;
        const unsigned long long v = s_acc[sg * PADU + cc];
        const unsigned int lo = (unsigned int)(v & 0xffffffffull);
        const unsigned int hi = (unsigned int)(v >> 32);
        unsafeAtomicAdd(&ws_pred[sg * CCH + c0 + cc], (float)lo);
        unsafeAtomicAdd(&ws_tgt[sg * CCH + c0 + cc],  (float)hi);
    }
    if (h == 0) {
        for (int i = tid; i < SEG; i += THREADS) {
            unsafeAtomicAdd(&ws_cnt[i], (float)s_cnt[i]);
        }
    }
}

__global__ void finalize_kernel(const float* __restrict__ ws, float* __restrict__ out) {
    const int t = blockIdx.x * blockDim.x + threadIdx.x;   // 0..2047 = b*512 + (label-1)
    if (t >= B_IMG * 512) return;
    const int b = t >> 9;
    const int l = (t & 511) + 1;

    const float cnt   = ws[WS_CNT + b * SEG + l];
    const float denom = fmaxf(cnt, 1.f);
    const float bias  = cnt * FXBIAS;

    const float* sp = ws + WS_PRED + (b * SEG + l) * CCH;
    const float* st = ws + WS_TGT  + (b * SEG + l) * CCH;
#pragma unroll
    for (int c = 0; c < CCH; ++c) {
        out[t * CCH + c]           = (sp[c] - bias) * FXINV / denom;
        out[OUT_TGT + t * CCH + c] = (st[c] - bias) * FXINV / denom;
    }
    // cell_ids written as float32 (d_out is read back as one fp32 buffer).
    out[OUT_CELL + t] = (cnt > 0.f) ? (float)l : 0.f;
}

extern "C" void kernel_launch(void* const* d_in, const int* in_sizes, int n_in,
                              void* d_out, int out_size, void* d_ws, size_t ws_size,
                              hipStream_t stream) {
    const float* pred   = (const float*)d_in[0];
    const float* target = (const float*)d_in[1];
    const int*   nuclei = (const int*)d_in[2];
    float* out = (float*)d_out;
    float* ws  = (float*)d_ws;

    hipMemsetAsync(d_ws, 0, WS_FLOATS * sizeof(float), stream);
    accum_kernel<<<GRID, THREADS, 0, stream>>>(pred, target, nuclei, ws);
    finalize_kernel<<<8, 256, 0, stream>>>(ws, out);
}